// Round 7
// baseline (3426.831 us; speedup 1.0000x reference)
//
#include <hip/hip_runtime.h>
#include <math.h>

#define BBATCH 32
#define NTOK 197
#define NPATCH 196
#define PDIM 768
#define DDIM 512
#define NHEAD 8
#define DHEAD 64
#define MLPDIM 2048
#define NLAYER 10
#define NCLASS 10
#define MTOK (BBATCH*NTOK)      // 6304
#define MPAD 6400               // padded rows (25*256)
#define MPATCH (BBATCH*NPATCH)  // 6272
#define QKVROWS (MTOK + 16)

typedef unsigned short u16;
typedef __attribute__((ext_vector_type(8))) short bf16x8;
typedef __attribute__((ext_vector_type(4))) float f32x4;

__device__ __forceinline__ float gelu_f(float x) {
    return 0.5f * x * (1.0f + erff(x * 0.70710678118654752440f));
}
__device__ __forceinline__ float bf2f(u16 u) {
    union { unsigned int i; float f; } v; v.i = ((unsigned int)u) << 16; return v.f;
}
__device__ __forceinline__ u16 f2bf(float f) {
    union { float f; unsigned int u; } v; v.f = f;
    unsigned int r = v.u + 0x7FFFu + ((v.u >> 16) & 1u);
    return (u16)(r >> 16);
}
__device__ __forceinline__ void gload_lds16(const u16* g, u16* l) {
    __builtin_amdgcn_global_load_lds((const __attribute__((address_space(1))) void*)g,
                                     (__attribute__((address_space(3))) void*)l, 16, 0, 0);
}

// ---------------------------------------------------------------------------
// Persistent multi-tile bf16 MFMA GEMM, 256x128 tiles, 512 thr = 8 waves,
// per-wave 64x64.  TRIPLE-buffered LDS ring + counted vmcnt(12): phase p+2's
// loads issue while phase p computes (2 phases of latency slack).  Blocks
// stream tiles back-to-back (tile = bid, bid+G, ...) so the pipe never drains
// until the block's last two phases (vmcnt 6 then 0).
// Two regions per dispatch (A: tiles [0,tilesA), B: rest).  Modes:
//   0 = bf16 out (no bias)       2 = gelu(acc+bias) -> bf16 out
//   1 = halt: sum_col gelu(acc+bias)*res[col] -> atomicAdd f32 per row
//   3 = f32 out = acc + bias (+ res[row][col] if res != null)
// ---------------------------------------------------------------------------
__global__ __launch_bounds__(512)
void pgemm_kernel(int tilesA, int colsA, int colsB, int tot, int K, int M,
                  const u16* __restrict__ Aa, const u16* __restrict__ Wa,
                  const float* __restrict__ biasa, const float* __restrict__ resa,
                  void* __restrict__ outa, int Na, int modeA,
                  const u16* __restrict__ Ab, const u16* __restrict__ Wb,
                  const float* __restrict__ biasb, const float* __restrict__ resb,
                  void* __restrict__ outb, int Nb, int modeB)
{
    __shared__ u16 As[3][256 * 64];   // 96 KB
    __shared__ u16 Bs[3][128 * 64];   // 48 KB
    const int tid = threadIdx.x, lane = tid & 63, wid = tid >> 6;
    const int wr = wid >> 1, wc = wid & 1;
    const int tile0 = blockIdx.x;
    if (tile0 >= tot) return;
    const int G = gridDim.x;
    const int nk = K >> 6;
    const int srow = tid >> 3, dcb = (tid & 7) << 4;

    // ---- stage cursor (tile being loaded) ----
    int sgT = tile0, sgK = 0, sgM = 0, sgN = 0;
    const u16 *sgA = Aa, *sgW = Wa;
    auto setSg = [&](int t) {
        if (t < tilesA) { sgA = Aa; sgW = Wa; sgM = (t / colsA) * 256; sgN = (t % colsA) * 128; }
        else { int lt = t - tilesA; sgA = Ab; sgW = Wb; sgM = (lt / colsB) * 256; sgN = (lt % colsB) * 128; }
    };
    setSg(sgT);
    auto sgStage = [&](int b) {
        int k0 = sgK << 6;
        #pragma unroll
        for (int p = 0; p < 4; ++p) {
            int rr = p * 64 + srow;
            int scb = dcb ^ ((rr & 7) << 4);
            gload_lds16(sgA + (size_t)(sgM + rr) * K + k0 + (scb >> 1), &As[b][p * 4096 + tid * 8]);
        }
        #pragma unroll
        for (int p = 0; p < 2; ++p) {
            int rr = p * 64 + srow;
            int scb = dcb ^ ((rr & 7) << 4);
            gload_lds16(sgW + (size_t)(sgN + rr) * K + k0 + (scb >> 1), &Bs[b][p * 4096 + tid * 8]);
        }
    };
    auto sgAdv = [&]() {
        if (++sgK == nk) { sgK = 0; sgT += G; if (sgT < tot) setSg(sgT); }
    };

    f32x4 acc[4][4] = {};
    auto compute = [&](int buf) {
        #pragma unroll
        for (int kk = 0; kk < 64; kk += 32) {
            const int kb = (kk + ((lane >> 4) << 3)) << 1;
            bf16x8 af[4], bfr[4];
            #pragma unroll
            for (int mi = 0; mi < 4; ++mi) {
                int ar = wr * 64 + mi * 16 + (lane & 15);
                af[mi] = *(const bf16x8*)&As[buf][ar * 64 + ((kb ^ ((ar & 7) << 4)) >> 1)];
            }
            #pragma unroll
            for (int ni = 0; ni < 4; ++ni) {
                int br = wc * 64 + ni * 16 + (lane & 15);
                bfr[ni] = *(const bf16x8*)&Bs[buf][br * 64 + ((kb ^ ((br & 7) << 4)) >> 1)];
            }
            #pragma unroll
            for (int mi = 0; mi < 4; ++mi)
                #pragma unroll
                for (int ni = 0; ni < 4; ++ni)
                    acc[mi][ni] = __builtin_amdgcn_mfma_f32_16x16x32_bf16(
                        af[mi], bfr[ni], acc[mi][ni], 0, 0, 0);
        }
    };

    // ---- prologue: stage phases 0 and 1 (nk >= 8 so both exist) ----
    sgStage(0); sgAdv();
    sgStage(1); sgAdv();
    int bufc = 0, pend = 2;

    for (int ct = tile0; ct < tot; ct += G) {
        // compute-side tile params (for epilogue)
        const float *bias, *res; void* out; int Nn, mode, m0, n0;
        if (ct < tilesA) {
            bias = biasa; res = resa; out = outa; Nn = Na; mode = modeA;
            m0 = (ct / colsA) * 256; n0 = (ct % colsA) * 128;
        } else {
            int lt = ct - tilesA;
            bias = biasb; res = resb; out = outb; Nn = Nb; mode = modeB;
            m0 = (lt / colsB) * 256; n0 = (lt % colsB) * 128;
        }
        #pragma unroll 1
        for (int k = 0; k < nk; ++k) {
            if (sgT < tot) {
                int bs = bufc + 2; if (bs >= 3) bs -= 3;
                sgStage(bs); sgAdv();
                asm volatile("s_waitcnt vmcnt(12)" ::: "memory");
            } else if (pend == 2) {
                pend = 1;
                asm volatile("s_waitcnt vmcnt(6)" ::: "memory");
            } else {
                asm volatile("s_waitcnt vmcnt(0)" ::: "memory");
            }
            __builtin_amdgcn_s_barrier();
            compute(bufc);
            if (k == nk - 1) {
                // ---- epilogue for tile ct ----
                if (mode == 1) {
                    float* hout = (float*)out;
                    #pragma unroll
                    for (int mi = 0; mi < 4; ++mi)
                        #pragma unroll
                        for (int j = 0; j < 4; ++j) {
                            int row = m0 + wr * 64 + mi * 16 + ((lane >> 4) << 2) + j;
                            float part = 0.0f;
                            #pragma unroll
                            for (int ni = 0; ni < 4; ++ni) {
                                int col = n0 + wc * 64 + ni * 16 + (lane & 15);
                                part += gelu_f(acc[mi][ni][j] + bias[col]) * res[col];
                            }
                            #pragma unroll
                            for (int off = 1; off < 16; off <<= 1) part += __shfl_xor(part, off, 64);
                            if ((lane & 15) == 0 && row < M) atomicAdd(&hout[row], part);
                        }
                } else if (mode == 3) {
                    float* outf = (float*)out;
                    #pragma unroll
                    for (int mi = 0; mi < 4; ++mi)
                        #pragma unroll
                        for (int j = 0; j < 4; ++j) {
                            int row = m0 + wr * 64 + mi * 16 + ((lane >> 4) << 2) + j;
                            if (row >= M) continue;
                            #pragma unroll
                            for (int ni = 0; ni < 4; ++ni) {
                                int col = n0 + wc * 64 + ni * 16 + (lane & 15);
                                float v = acc[mi][ni][j] + bias[col];
                                if (res) v += res[(size_t)row * Nn + col];
                                outf[(size_t)row * Nn + col] = v;
                            }
                        }
                } else {
                    u16* ob = (u16*)out;
                    #pragma unroll
                    for (int mi = 0; mi < 4; ++mi)
                        #pragma unroll
                        for (int j = 0; j < 4; ++j) {
                            int row = m0 + wr * 64 + mi * 16 + ((lane >> 4) << 2) + j;
                            if (row >= M) continue;
                            #pragma unroll
                            for (int ni = 0; ni < 4; ++ni) {
                                int col = n0 + wc * 64 + ni * 16 + (lane & 15);
                                float v = acc[mi][ni][j];
                                if (mode == 2) v = gelu_f(v + bias[col]);
                                ob[(size_t)row * Nn + col] = f2bf(v);
                            }
                        }
                }
            }
            __builtin_amdgcn_s_barrier();
            bufc = (bufc == 2) ? 0 : bufc + 1;
        }
        #pragma unroll
        for (int mi = 0; mi < 4; ++mi)
            #pragma unroll
            for (int ni = 0; ni < 4; ++ni)
                acc[mi][ni] = (f32x4){0.f, 0.f, 0.f, 0.f};
    }
}

// ---------------------------------------------------------------------------
// LayerNorm: one wave per row (grid-strided), fp32 in, one or two bf16 outs.
// ---------------------------------------------------------------------------
__global__ __launch_bounds__(256)
void ln_one_kernel(const float* __restrict__ X, const float* __restrict__ g,
                   const float* __restrict__ bb, u16* __restrict__ Y, int M)
{
    int w0 = blockIdx.x * 4 + (threadIdx.x >> 6);
    int lane = threadIdx.x & 63;
    int stride = gridDim.x * 4;
    for (int row = w0; row < M; row += stride) {
        const float* x = X + (size_t)row * DDIM;
        float v[8], s = 0.0f;
        #pragma unroll
        for (int i = 0; i < 8; i++) { v[i] = x[lane + i * 64]; s += v[i]; }
        #pragma unroll
        for (int off = 32; off; off >>= 1) s += __shfl_xor(s, off, 64);
        float mu = s * (1.0f / 512.0f), q = 0.0f;
        #pragma unroll
        for (int i = 0; i < 8; i++) { float d = v[i] - mu; q += d * d; }
        #pragma unroll
        for (int off = 32; off; off >>= 1) q += __shfl_xor(q, off, 64);
        float inv = 1.0f / sqrtf(q * (1.0f / 512.0f) + 1e-5f);
        u16* y = Y + (size_t)row * DDIM;
        #pragma unroll
        for (int i = 0; i < 8; i++) {
            int c = lane + i * 64;
            y[c] = f2bf((v[i] - mu) * inv * g[c] + bb[c]);
        }
    }
}

__global__ __launch_bounds__(256)
void ln_dual_kernel(const float* __restrict__ X,
                    const float* __restrict__ g1, const float* __restrict__ b1,
                    const float* __restrict__ g2, const float* __restrict__ b2,
                    u16* __restrict__ Y1, u16* __restrict__ Y2, int M)
{
    int w0 = blockIdx.x * 4 + (threadIdx.x >> 6);
    int lane = threadIdx.x & 63;
    int stride = gridDim.x * 4;
    for (int row = w0; row < M; row += stride) {
        const float* x = X + (size_t)row * DDIM;
        float v[8], s = 0.0f;
        #pragma unroll
        for (int i = 0; i < 8; i++) { v[i] = x[lane + i * 64]; s += v[i]; }
        #pragma unroll
        for (int off = 32; off; off >>= 1) s += __shfl_xor(s, off, 64);
        float mu = s * (1.0f / 512.0f), q = 0.0f;
        #pragma unroll
        for (int i = 0; i < 8; i++) { float d = v[i] - mu; q += d * d; }
        #pragma unroll
        for (int off = 32; off; off >>= 1) q += __shfl_xor(q, off, 64);
        float inv = 1.0f / sqrtf(q * (1.0f / 512.0f) + 1e-5f);
        u16* y1 = Y1 + (size_t)row * DDIM;
        u16* y2 = Y2 + (size_t)row * DDIM;
        #pragma unroll
        for (int i = 0; i < 8; i++) {
            int c = lane + i * 64;
            float n = (v[i] - mu) * inv;
            y1[c] = f2bf(n * g1[c] + b1[c]);
            y2[c] = f2bf(n * g2[c] + b2[c]);
        }
    }
}

__global__ __launch_bounds__(256)
void patch_kernel(const float* __restrict__ x, u16* __restrict__ xp)
{
    const size_t total = (size_t)MPATCH * PDIM;
    for (size_t idx = (size_t)blockIdx.x * 256 + threadIdx.x; idx < total;
         idx += (size_t)gridDim.x * 256) {
        int pd = (int)(idx % PDIM);
        int bn = (int)(idx / PDIM);
        int n = bn % NPATCH, b = bn / NPATCH;
        int c = pd % 3, pix = pd / 3;
        int px = pix % 16, py = pix / 16;
        int hx = n % 14, hy = n / 14;
        int row = hy * 16 + py, col = hx * 16 + px;
        xp[idx] = f2bf(x[((size_t)(b * 3 + c) * 224 + row) * 224 + col]);
    }
}

__global__ __launch_bounds__(256)
void assemble_kernel(const float* __restrict__ e, const float* __restrict__ clstok,
                     const float* __restrict__ pos, float* __restrict__ U)
{
    const size_t total = (size_t)MTOK * DDIM;
    for (size_t idx = (size_t)blockIdx.x * 256 + threadIdx.x; idx < total;
         idx += (size_t)gridDim.x * 256) {
        int d = (int)(idx % DDIM);
        int bt = (int)(idx / DDIM);
        int t = bt % NTOK, b = bt / NTOK;
        float v = (t == 0) ? clstok[d] : e[((size_t)b * NPATCH + (t - 1)) * DDIM + d];
        U[idx] = v + pos[t * DDIM + d];
    }
}

__global__ __launch_bounds__(256)
void convert7_kernel(const float* s0, const float* s1, const float* s2,
                     const float* s3, const float* s4, const float* s5,
                     const float* s6, u16* __restrict__ dst)
{
    const int total4 = 1409024;  // 5636096/4
    for (int i4 = blockIdx.x * 256 + threadIdx.x; i4 < total4; i4 += gridDim.x * 256) {
        size_t e = (size_t)i4 * 4;
        const float* s; size_t off;
        if      (e < 393216)  { s = s0; off = 0; }
        else if (e < 1179648) { s = s1; off = 393216; }
        else if (e < 1441792) { s = s2; off = 1179648; }
        else if (e < 2490368) { s = s3; off = 1441792; }
        else if (e < 3538944) { s = s4; off = 2490368; }
        else if (e < 4587520) { s = s5; off = 3538944; }
        else                  { s = s6; off = 4587520; }
        float4 v = ((const float4*)s)[(e - off) >> 2];
        dst[e + 0] = f2bf(v.x); dst[e + 1] = f2bf(v.y);
        dst[e + 2] = f2bf(v.z); dst[e + 3] = f2bf(v.w);
    }
}

// ---------------------------------------------------------------------------
// MFMA attention (blocks 0..511) with optional fused halt-mean (blocks 512+).
// ---------------------------------------------------------------------------
template<int HM>
__global__ __launch_bounds__(256)
void attn_hm_kernel(const u16* __restrict__ qkv, u16* __restrict__ O,
                    const float* __restrict__ hsc, const float* __restrict__ bh2,
                    const float* __restrict__ U, float* __restrict__ halts,
                    float* __restrict__ cls, int lidx)
{
    __shared__ u16 Ks[208 * 64];
    __shared__ u16 Vt[64 * 208];
    __shared__ u16 Pl[4 * 16 * 208];

    if (HM && blockIdx.x >= 512) {
        int b = blockIdx.x - 512;
        int ln = threadIdx.x;
        if (ln >= 64) return;
        float bb = bh2[0];
        float s = 0.0f;
        for (int t = ln; t < NTOK; t += 64)
            s += 1.0f / (1.0f + expf(-(hsc[b * NTOK + t] + bb)));
        #pragma unroll
        for (int off = 32; off; off >>= 1) s += __shfl_xor(s, off, 64);
        if (ln == 0) halts[b * NLAYER + lidx] = s * (1.0f / (float)NTOK);
        for (int d = ln; d < DDIM; d += 64)
            cls[((size_t)b * NLAYER + lidx) * DDIM + d] = U[(size_t)b * NTOK * DDIM + d];
        return;
    }

    const int bh = blockIdx.x >> 1;
    const int half = blockIdx.x & 1;
    const int b = bh >> 3, h = bh & 7;
    const int tid = threadIdx.x;
    const int lane = tid & 63, wid = tid >> 6;
    const size_t base = ((size_t)b * NTOK) * 1536 + (size_t)h * 64;

    {
        int j0 = tid >> 3;
        int d0 = (tid & 7) * 8;
        for (int p = 0; p < 7; ++p) {
            int j = p * 32 + j0;
            if (j < 208) {
                bf16x8 v = {};
                if (j < NTOK) v = *(const bf16x8*)&qkv[base + (size_t)j * 1536 + 512 + d0];
                int byt = (j * 128 + d0 * 2) ^ ((j & 7) << 4);
                *(bf16x8*)((char*)Ks + byt) = v;
            }
        }
    }
    {
        int d = tid & 63;
        int jg = tid >> 6;
        for (int j = jg * 52; j < jg * 52 + 52; ++j) {
            u16 v = (j < NTOK) ? qkv[base + (size_t)j * 1536 + 1024 + d] : (u16)0;
            int byt = (d * 416 + j * 2) ^ ((d & 7) << 4);
            *(u16*)((char*)Vt + byt) = v;
        }
    }
    __syncthreads();

    u16* Pw = Pl + wid * 16 * 208;
    const float scale = 0.04419417382415922f;
    const int t0   = half ? 7 : 0;
    const int tcnt = half ? 6 : 7;
    const int g = lane >> 4;
    const int mycol = lane & 15;

    for (int ti = wid; ti < tcnt; ti += 4) {
        const int r0 = (t0 + ti) * 16;
        bf16x8 qf[2];
        #pragma unroll
        for (int ks = 0; ks < 2; ++ks) {
            int row = r0 + mycol;
            int col = ks * 32 + (g << 3);
            qf[ks] = *(const bf16x8*)&qkv[base + (size_t)row * 1536 + col];
        }
        f32x4 s[13];
        #pragma unroll
        for (int ct = 0; ct < 13; ++ct) s[ct] = (f32x4){0.f, 0.f, 0.f, 0.f};
        #pragma unroll
        for (int ks = 0; ks < 2; ++ks) {
            int kbyte = (ks * 32 + (g << 3)) * 2;
            #pragma unroll
            for (int ct = 0; ct < 13; ++ct) {
                int n = ct * 16 + mycol;
                bf16x8 kf = *(const bf16x8*)((char*)Ks + ((n * 128 + kbyte) ^ ((n & 7) << 4)));
                s[ct] = __builtin_amdgcn_mfma_f32_16x16x32_bf16(qf[ks], kf, s[ct], 0, 0, 0);
            }
        }
        float m[4], sum[4];
        #pragma unroll
        for (int j = 0; j < 4; ++j) m[j] = -1e30f;
        #pragma unroll
        for (int ct = 0; ct < 13; ++ct) {
            bool valid = (ct * 16 + mycol) < NTOK;
            #pragma unroll
            for (int j = 0; j < 4; ++j) {
                float v = valid ? s[ct][j] * scale : -1e30f;
                s[ct][j] = v;
                m[j] = fmaxf(m[j], v);
            }
        }
        #pragma unroll
        for (int off = 1; off < 16; off <<= 1)
            #pragma unroll
            for (int j = 0; j < 4; ++j) m[j] = fmaxf(m[j], __shfl_xor(m[j], off, 64));
        #pragma unroll
        for (int j = 0; j < 4; ++j) sum[j] = 0.0f;
        #pragma unroll
        for (int ct = 0; ct < 13; ++ct)
            #pragma unroll
            for (int j = 0; j < 4; ++j) {
                float e = expf(s[ct][j] - m[j]);
                s[ct][j] = e;
                sum[j] += e;
            }
        #pragma unroll
        for (int off = 1; off < 16; off <<= 1)
            #pragma unroll
            for (int j = 0; j < 4; ++j) sum[j] += __shfl_xor(sum[j], off, 64);
        float inv[4];
        #pragma unroll
        for (int j = 0; j < 4; ++j) inv[j] = 1.0f / sum[j];
        #pragma unroll
        for (int ct = 0; ct < 13; ++ct) {
            int col = ct * 16 + mycol;
            #pragma unroll
            for (int j = 0; j < 4; ++j) {
                int row = (g << 2) + j;
                int byt = (row * 416 + col * 2) ^ ((row & 7) << 4);
                *(u16*)((char*)Pw + byt) = f2bf(s[ct][j] * inv[j]);
            }
        }
        #pragma unroll
        for (int nt = 0; nt < 4; ++nt) {
            f32x4 o = (f32x4){0.f, 0.f, 0.f, 0.f};
            #pragma unroll
            for (int ks = 0; ks < 7; ++ks) {
                bf16x8 pf = {}, vf = {};
                bool live = !(ks == 6 && g >= 2);
                if (live) {
                    int kbyte = (ks * 32 + (g << 3)) * 2;
                    pf = *(const bf16x8*)((char*)Pw + ((mycol * 416 + kbyte) ^ ((mycol & 7) << 4)));
                    int vrow = nt * 16 + mycol;
                    vf = *(const bf16x8*)((char*)Vt + ((vrow * 416 + kbyte) ^ ((vrow & 7) << 4)));
                }
                o = __builtin_amdgcn_mfma_f32_16x16x32_bf16(pf, vf, o, 0, 0, 0);
            }
            #pragma unroll
            for (int j = 0; j < 4; ++j) {
                int grow = r0 + (g << 2) + j;
                if (grow < NTOK)
                    O[((size_t)b * NTOK + grow) * DDIM + h * 64 + nt * 16 + mycol] = f2bf(o[j]);
            }
        }
    }
}

__global__ __launch_bounds__(64)
void haltmean_kernel(const float* __restrict__ hsc, const float* __restrict__ bh2,
                     const float* __restrict__ U, float* __restrict__ halts,
                     float* __restrict__ cls, int lidx)
{
    int b = blockIdx.x, lane = threadIdx.x;
    float bb = bh2[0];
    float s = 0.0f;
    for (int t = lane; t < NTOK; t += 64)
        s += 1.0f / (1.0f + expf(-(hsc[b * NTOK + t] + bb)));
    #pragma unroll
    for (int off = 32; off; off >>= 1) s += __shfl_xor(s, off, 64);
    if (lane == 0) halts[b * NLAYER + lidx] = s * (1.0f / (float)NTOK);
    for (int d = lane; d < DDIM; d += 64)
        cls[((size_t)b * NLAYER + lidx) * DDIM + d] = U[(size_t)b * NTOK * DDIM + d];
}

__global__ __launch_bounds__(256)
void head_logits_kernel(const u16* __restrict__ Hh, const float* __restrict__ Wc2,
                        const float* __restrict__ bc2, float* __restrict__ logits)
{
    int wave = (blockIdx.x * 4) + (threadIdx.x >> 6);
    int lane = threadIdx.x & 63;
    if (wave >= BBATCH * NLAYER) return;
    const u16* row = Hh + (size_t)wave * MLPDIM;
    float rv[32];
    #pragma unroll
    for (int i = 0; i < 32; i++) rv[i] = bf2f(row[lane + i * 64]);
    #pragma unroll
    for (int c = 0; c < NCLASS; c++) {
        float s = 0.0f;
        #pragma unroll
        for (int i = 0; i < 32; i++) s = fmaf(rv[i], Wc2[c * MLPDIM + lane + i * 64], s);
        #pragma unroll
        for (int off = 32; off; off >>= 1) s += __shfl_xor(s, off, 64);
        if (lane == 0) logits[wave * NCLASS + c] = s + bc2[c];
    }
}

__global__ __launch_bounds__(256)
void celoss_kernel(const float* __restrict__ logits, const int* __restrict__ y,
                   const float* __restrict__ halts, float* __restrict__ out)
{
    __shared__ float ceS[BBATCH * NLAYER];
    __shared__ float bl[BBATCH];
    int tid = threadIdx.x;
    for (int r = tid; r < BBATCH * NLAYER; r += 256) {
        const float* lg = logits + (size_t)r * NCLASS;
        float mx = lg[0];
        #pragma unroll
        for (int i = 1; i < NCLASS; i++) mx = fmaxf(mx, lg[i]);
        float s = 0.0f;
        #pragma unroll
        for (int i = 0; i < NCLASS; i++) s += expf(lg[i] - mx);
        int lab = y[r / NLAYER];
        ceS[r] = -(lg[lab] - mx - logf(s));
    }
    __syncthreads();
    if (tid < BBATCH) {
        const float* c = ceS + tid * NLAYER;
        int idx = 0; float mn = c[0];
        for (int l = 1; l < NLAYER; l++) if (c[l] < mn) { mn = c[l]; idx = l; }
        idx += 1;
        float acc = 0.0f;
        for (int l = 0; l < idx; l++) {
            acc += c[l];
            float p = halts[tid * NLAYER + l];
            p = fminf(fmaxf(p, 1e-7f), 1.0f - 1e-7f);
            float hl = (l == idx - 1) ? 0.0f : 1.0f;
            acc += -(hl * logf(p) + (1.0f - hl) * log1pf(-p));
        }
        bl[tid] = acc / (float)idx;
    }
    __syncthreads();
    if (tid == 0) {
        float t = 0.0f;
        for (int b = 0; b < BBATCH; b++) t += bl[b];
        out[0] = t * (1.0f / (float)BBATCH);
    }
}

extern "C" void kernel_launch(void* const* d_in, const int* in_sizes, int n_in,
                              void* d_out, int out_size, void* d_ws, size_t ws_size,
                              hipStream_t stream)
{
    const float* x      = (const float*)d_in[0];
    const int*   y      = (const int*)d_in[1];
    const float* pos    = (const float*)d_in[2];
    const float* clstok = (const float*)d_in[3];
    const float* Wp     = (const float*)d_in[4];
    const float* bp     = (const float*)d_in[5];
    const float* Wqkv   = (const float*)d_in[6];
    const float* Wo     = (const float*)d_in[7];
    const float* bo     = (const float*)d_in[8];
    const float* ln1g   = (const float*)d_in[9];
    const float* ln1b   = (const float*)d_in[10];
    const float* ln2g   = (const float*)d_in[11];
    const float* ln2b   = (const float*)d_in[12];
    const float* W1     = (const float*)d_in[13];
    const float* b1     = (const float*)d_in[14];
    const float* W2     = (const float*)d_in[15];
    const float* b2     = (const float*)d_in[16];
    const float* lnhg   = (const float*)d_in[17];
    const float* lnhb   = (const float*)d_in[18];
    const float* Wh1    = (const float*)d_in[19];
    const float* bh1    = (const float*)d_in[20];
    const float* Wh2    = (const float*)d_in[21];
    const float* bh2    = (const float*)d_in[22];
    const float* lncg   = (const float*)d_in[23];
    const float* lncb   = (const float*)d_in[24];
    const float* Wc1    = (const float*)d_in[25];
    const float* bc1    = (const float*)d_in[26];
    const float* Wc2    = (const float*)d_in[27];
    const float* bc2    = (const float*)d_in[28];

    // ---- workspace layout ----
    float* U      = (float*)d_ws;                         // MTOK*512 f32
    float* CLS    = U + (size_t)MTOK * DDIM;              // 320*512
    float* LOGITS = CLS + (size_t)BBATCH * NLAYER * DDIM; // 3200
    float* HSC    = LOGITS + BBATCH * NLAYER * NCLASS;    // 10*MTOK
    float* HALTS  = HSC + (size_t)NLAYER * MTOK;          // 320
    u16* QKVb = (u16*)(HALTS + BBATCH * NLAYER + 32);     // QKVROWS*1536 (aliases EMB)
    float* EMB = (float*)QKVb;                            // MPATCH*512 f32 (pre-loop only)
    u16* LNB1 = QKVb + (size_t)QKVROWS * 1536;            // MPAD*512
    u16* LNB2 = LNB1 + (size_t)MPAD * DDIM;               // MPAD*512
    u16* LNBh = LNB2 + (size_t)MPAD * DDIM;               // MPAD*512
    u16* HB   = LNBh + (size_t)MPAD * DDIM;               // MPAD*2048 (aliases XP)
    u16* XP   = HB;                                       // MPATCH*768 (pre-loop only)
    u16* CLNB = HB + (size_t)MPAD * MLPDIM;               // 384*512
    u16* wWp  = CLNB + 384 * DDIM;
    u16* wWqkv= wWp   + 512 * 768;
    u16* wWo  = wWqkv + 1536 * 512;
    u16* wW1  = wWo   + 512 * 512;
    u16* wW2  = wW1   + 2048 * 512;
    u16* wWh1 = wW2   + 512 * 2048;
    u16* wWc1 = wWh1  + 2048 * 512;

    dim3 blk(256);
    const float* dummyF = bh2;

    // ---- setup ----
    convert7_kernel<<<dim3(1024), blk, 0, stream>>>(Wp, Wqkv, Wo, W1, W2, Wh1, Wc1, wWp);
    hipMemsetAsync(HSC, 0, (size_t)NLAYER * MTOK * sizeof(float), stream);
    patch_kernel<<<dim3(2048), blk, 0, stream>>>(x, XP);
    pgemm_kernel<<<dim3(100), dim3(512), 0, stream>>>(
        100, 4, 1, 100, PDIM, MPATCH,
        XP, wWp, bp, nullptr, (void*)EMB, DDIM, 3,
        XP, wWp, bp, nullptr, (void*)EMB, DDIM, 3);
    assemble_kernel<<<dim3(2048), blk, 0, stream>>>(EMB, clstok, pos, U);
    ln_dual_kernel<<<dim3(256), blk, 0, stream>>>(U, ln1g, ln1b, lnhg, lnhb, LNB1, LNBh, MTOK);

    for (int l = 0; l < NLAYER; l++) {
        // 1: QKV GEMM (+ halt GEMM of layer l-1)
        if (l == 0) {
            pgemm_kernel<<<dim3(256), dim3(512), 0, stream>>>(
                300, 12, 1, 300, DDIM, MTOK,
                LNB1, wWqkv, nullptr, nullptr, (void*)QKVb, 1536, 0,
                LNB1, wWqkv, nullptr, nullptr, (void*)QKVb, 1536, 0);
        } else {
            pgemm_kernel<<<dim3(256), dim3(512), 0, stream>>>(
                300, 12, 16, 700, DDIM, MTOK,
                LNB1, wWqkv, nullptr, nullptr, (void*)QKVb, 1536, 0,
                LNBh, wWh1, bh1, Wh2, (void*)(HSC + (size_t)(l - 1) * MTOK), 2048, 1);
        }
        // 2: attn (+ halt-mean of layer l-1)
        if (l == 0) {
            attn_hm_kernel<0><<<dim3(512), blk, 0, stream>>>(
                QKVb, LNB1, nullptr, dummyF, U, HALTS, CLS, 0);
        } else {
            attn_hm_kernel<1><<<dim3(544), blk, 0, stream>>>(
                QKVb, LNB1, HSC + (size_t)(l - 1) * MTOK, bh2, U, HALTS, CLS, l - 1);
        }
        // 3: Wo + bias + residual -> U (f32)
        pgemm_kernel<<<dim3(100), dim3(512), 0, stream>>>(
            100, 4, 1, 100, DDIM, MTOK,
            LNB1, wWo, bo, U, (void*)U, DDIM, 3,
            LNB1, wWo, bo, U, (void*)U, DDIM, 3);
        // 4: ln2
        ln_one_kernel<<<dim3(256), blk, 0, stream>>>(U, ln2g, ln2b, LNB2, MTOK);
        // 5: W1 + bias + gelu -> HB (bf16)
        pgemm_kernel<<<dim3(256), dim3(512), 0, stream>>>(
            400, 16, 1, 400, DDIM, MTOK,
            LNB2, wW1, b1, nullptr, (void*)HB, MLPDIM, 2,
            LNB2, wW1, b1, nullptr, (void*)HB, MLPDIM, 2);
        // 6: W2 + bias + residual -> U (f32), K=2048 (32-deep pipeline)
        pgemm_kernel<<<dim3(100), dim3(512), 0, stream>>>(
            100, 4, 1, 100, MLPDIM, MTOK,
            HB, wW2, b2, U, (void*)U, DDIM, 3,
            HB, wW2, b2, U, (void*)U, DDIM, 3);
        // 7: fused ln1 + lnh of new U
        ln_dual_kernel<<<dim3(256), blk, 0, stream>>>(
            U, ln1g, ln1b, lnhg, lnhb, LNB1, LNBh, MTOK);
    }

    // final halt GEMM (layer 9) + halt-mean
    pgemm_kernel<<<dim3(256), dim3(512), 0, stream>>>(
        400, 16, 1, 400, DDIM, MTOK,
        LNBh, wWh1, bh1, Wh2, (void*)(HSC + (size_t)9 * MTOK), 2048, 1,
        LNBh, wWh1, bh1, Wh2, (void*)(HSC + (size_t)9 * MTOK), 2048, 1);
    haltmean_kernel<<<dim3(BBATCH), dim3(64), 0, stream>>>(
        HSC + (size_t)9 * MTOK, bh2, U, HALTS, CLS, 9);

    // head
    ln_one_kernel<<<dim3(80), blk, 0, stream>>>(CLS, lncg, lncb, CLNB, BBATCH * NLAYER);
    pgemm_kernel<<<dim3(32), dim3(512), 0, stream>>>(
        32, 16, 1, 32, DDIM, BBATCH * NLAYER,
        CLNB, wWc1, bc1, nullptr, (void*)HB, MLPDIM, 2,
        CLNB, wWc1, bc1, nullptr, (void*)HB, MLPDIM, 2);
    head_logits_kernel<<<dim3(80), blk, 0, stream>>>(HB, Wc2, bc2, LOGITS);
    celoss_kernel<<<dim3(1), blk, 0, stream>>>(LOGITS, y, HALTS, (float*)d_out);
}

// Round 8
// 2518.125 us; speedup vs baseline: 1.3609x; 1.3609x over previous
//
#include <hip/hip_runtime.h>
#include <math.h>

#define BBATCH 32
#define NTOK 197
#define NPATCH 196
#define PDIM 768
#define DDIM 512
#define NHEAD 8
#define DHEAD 64
#define MLPDIM 2048
#define NLAYER 10
#define NCLASS 10
#define MTOK (BBATCH*NTOK)      // 6304
#define MPAD 6400               // padded rows (50*128)
#define MPATCH (BBATCH*NPATCH)  // 6272
#define QKVROWS (MTOK + 16)

typedef unsigned short u16;
typedef __attribute__((ext_vector_type(8))) short bf16x8;
typedef __attribute__((ext_vector_type(4))) float f32x4;

__device__ __forceinline__ float gelu_f(float x) {
    return 0.5f * x * (1.0f + erff(x * 0.70710678118654752440f));
}
__device__ __forceinline__ float bf2f(u16 u) {
    union { unsigned int i; float f; } v; v.i = ((unsigned int)u) << 16; return v.f;
}
__device__ __forceinline__ u16 f2bf(float f) {
    union { float f; unsigned int u; } v; v.f = f;
    unsigned int r = v.u + 0x7FFFu + ((v.u >> 16) & 1u);
    return (u16)(r >> 16);
}
__device__ __forceinline__ void gload_lds16(const u16* g, u16* l) {
    __builtin_amdgcn_global_load_lds((const __attribute__((address_space(1))) void*)g,
                                     (__attribute__((address_space(3))) void*)l, 16, 0, 0);
}
__device__ __forceinline__ int swz_bij(int wg, int nwg) {
    int q = nwg >> 3, r = nwg & 7, xcd = wg & 7, id8 = wg >> 3;
    return (xcd < r) ? xcd * (q + 1) + id8 : r * (q + 1) + (xcd - r) * q + id8;
}

// ---------------------------------------------------------------------------
// Unified 128x128-tile bf16 MFMA GEMM. 256 thr = 4 waves (2x2), 64x64/wave.
// SINGLE-buffered LDS (32 KB) -> 5 blocks/CU co-resident; per-phase
// {stage; vmcnt(0); barrier; compute; barrier} (m97 structure — stalls are
// hidden by cross-block overlap, not intra-block pipelining).
// Two regions per dispatch (blocks [0,tilesA) = region A, rest = region B).
// Modes: 0 = bf16 out (no bias)        2 = gelu(acc+bias) -> bf16 out
//        1 = halt: sum_col gelu(acc+bias)*res[col] -> atomicAdd f32 per row
//        3 = f32 out = acc + bias (+ res[row][col] if res)
//        4 = f32 atomicAdd out += acc (+ bias[col] if bias)   [split-K]
// ---------------------------------------------------------------------------
__global__ __launch_bounds__(256)
void mg_kernel(int tilesA, int K, int M,
               const u16* __restrict__ Aa, const u16* __restrict__ Wa,
               const float* __restrict__ ba, const float* __restrict__ ra,
               void* __restrict__ oa, int Na, int modeA, int colsA, int kbA, int nkA,
               const u16* __restrict__ Ab, const u16* __restrict__ Wb,
               const float* __restrict__ bb, const float* __restrict__ rb,
               void* __restrict__ ob, int Nb, int modeB, int colsB, int kbB, int nkB)
{
    __shared__ u16 As[128 * 64];
    __shared__ u16 Bs[128 * 64];
    const int tid = threadIdx.x, lane = tid & 63, wid = tid >> 6;
    const int wr = wid >> 1, wc = wid & 1;

    const int swz = swz_bij(blockIdx.x, gridDim.x);
    const u16 *A, *W; const float *bias, *res; void* out;
    int Nn, mode, kb, nk, ti, cols;
    if (swz < tilesA) {
        A = Aa; W = Wa; bias = ba; res = ra; out = oa;
        Nn = Na; mode = modeA; cols = colsA; kb = kbA; nk = nkA; ti = swz;
    } else {
        A = Ab; W = Wb; bias = bb; res = rb; out = ob;
        Nn = Nb; mode = modeB; cols = colsB; kb = kbB; nk = nkB; ti = swz - tilesA;
    }
    const int m0 = (ti / cols) * 128, n0 = (ti % cols) * 128;

    f32x4 acc[4][4] = {};
    const int srow = tid >> 3;
    const int dcb  = (tid & 7) << 4;

    auto stage = [&](int k0) {
        #pragma unroll
        for (int p = 0; p < 4; ++p) {
            int rr = p * 32 + srow;
            int scb = dcb ^ ((rr & 7) << 4);
            gload_lds16(A + (size_t)(m0 + rr) * K + k0 + (scb >> 1), &As[p * 2048 + tid * 8]);
            gload_lds16(W + (size_t)(n0 + rr) * K + k0 + (scb >> 1), &Bs[p * 2048 + tid * 8]);
        }
    };
    auto compute = [&]() {
        #pragma unroll
        for (int kk = 0; kk < 64; kk += 32) {
            const int kbyte = (kk + ((lane >> 4) << 3)) << 1;
            bf16x8 af[4], bfr[4];
            #pragma unroll
            for (int mi = 0; mi < 4; ++mi) {
                int ar = wr * 64 + mi * 16 + (lane & 15);
                af[mi] = *(const bf16x8*)&As[ar * 64 + ((kbyte ^ ((ar & 7) << 4)) >> 1)];
            }
            #pragma unroll
            for (int ni = 0; ni < 4; ++ni) {
                int br = wc * 64 + ni * 16 + (lane & 15);
                bfr[ni] = *(const bf16x8*)&Bs[br * 64 + ((kbyte ^ ((br & 7) << 4)) >> 1)];
            }
            #pragma unroll
            for (int mi = 0; mi < 4; ++mi)
                #pragma unroll
                for (int ni = 0; ni < 4; ++ni)
                    acc[mi][ni] = __builtin_amdgcn_mfma_f32_16x16x32_bf16(
                        af[mi], bfr[ni], acc[mi][ni], 0, 0, 0);
        }
    };

    #pragma unroll 1
    for (int t = 0; t < nk; ++t) {
        stage(kb + (t << 6));
        asm volatile("s_waitcnt vmcnt(0)" ::: "memory");
        __builtin_amdgcn_s_barrier();
        compute();
        __builtin_amdgcn_s_barrier();
    }

    if (mode == 1) {
        float* hout = (float*)out;
        #pragma unroll
        for (int mi = 0; mi < 4; ++mi)
            #pragma unroll
            for (int j = 0; j < 4; ++j) {
                int row = m0 + wr * 64 + mi * 16 + ((lane >> 4) << 2) + j;
                float part = 0.0f;
                #pragma unroll
                for (int ni = 0; ni < 4; ++ni) {
                    int col = n0 + wc * 64 + ni * 16 + (lane & 15);
                    part += gelu_f(acc[mi][ni][j] + bias[col]) * res[col];
                }
                #pragma unroll
                for (int off = 1; off < 16; off <<= 1) part += __shfl_xor(part, off, 64);
                if ((lane & 15) == 0 && row < M) atomicAdd(&hout[row], part);
            }
        return;
    }
    if (mode == 4) {
        float* outf = (float*)out;
        #pragma unroll
        for (int mi = 0; mi < 4; ++mi)
            #pragma unroll
            for (int j = 0; j < 4; ++j) {
                int row = m0 + wr * 64 + mi * 16 + ((lane >> 4) << 2) + j;
                if (row >= M) continue;
                #pragma unroll
                for (int ni = 0; ni < 4; ++ni) {
                    int col = n0 + wc * 64 + ni * 16 + (lane & 15);
                    float v = acc[mi][ni][j];
                    if (bias) v += bias[col];
                    atomicAdd(&outf[(size_t)row * Nn + col], v);
                }
            }
        return;
    }
    if (mode == 3) {
        float* outf = (float*)out;
        #pragma unroll
        for (int mi = 0; mi < 4; ++mi)
            #pragma unroll
            for (int j = 0; j < 4; ++j) {
                int row = m0 + wr * 64 + mi * 16 + ((lane >> 4) << 2) + j;
                if (row >= M) continue;
                #pragma unroll
                for (int ni = 0; ni < 4; ++ni) {
                    int col = n0 + wc * 64 + ni * 16 + (lane & 15);
                    float v = acc[mi][ni][j] + bias[col];
                    if (res) v += res[(size_t)row * Nn + col];
                    outf[(size_t)row * Nn + col] = v;
                }
            }
        return;
    }
    u16* ob16 = (u16*)out;
    #pragma unroll
    for (int mi = 0; mi < 4; ++mi)
        #pragma unroll
        for (int j = 0; j < 4; ++j) {
            int row = m0 + wr * 64 + mi * 16 + ((lane >> 4) << 2) + j;
            if (row >= M) continue;
            #pragma unroll
            for (int ni = 0; ni < 4; ++ni) {
                int col = n0 + wc * 64 + ni * 16 + (lane & 15);
                float v = acc[mi][ni][j];
                if (mode == 2) v = gelu_f(v + bias[col]);
                ob16[(size_t)row * Nn + col] = f2bf(v);
            }
        }
}

// ---------------------------------------------------------------------------
// LayerNorm: one wave per row (grid-strided), fp32 in, one or two bf16 outs.
// ---------------------------------------------------------------------------
__global__ __launch_bounds__(256)
void ln_one_kernel(const float* __restrict__ X, const float* __restrict__ g,
                   const float* __restrict__ bb, u16* __restrict__ Y, int M)
{
    int w0 = blockIdx.x * 4 + (threadIdx.x >> 6);
    int lane = threadIdx.x & 63;
    int stride = gridDim.x * 4;
    for (int row = w0; row < M; row += stride) {
        const float* x = X + (size_t)row * DDIM;
        float v[8], s = 0.0f;
        #pragma unroll
        for (int i = 0; i < 8; i++) { v[i] = x[lane + i * 64]; s += v[i]; }
        #pragma unroll
        for (int off = 32; off; off >>= 1) s += __shfl_xor(s, off, 64);
        float mu = s * (1.0f / 512.0f), q = 0.0f;
        #pragma unroll
        for (int i = 0; i < 8; i++) { float d = v[i] - mu; q += d * d; }
        #pragma unroll
        for (int off = 32; off; off >>= 1) q += __shfl_xor(q, off, 64);
        float inv = 1.0f / sqrtf(q * (1.0f / 512.0f) + 1e-5f);
        u16* y = Y + (size_t)row * DDIM;
        #pragma unroll
        for (int i = 0; i < 8; i++) {
            int c = lane + i * 64;
            y[c] = f2bf((v[i] - mu) * inv * g[c] + bb[c]);
        }
    }
}

__global__ __launch_bounds__(256)
void ln_dual_kernel(const float* __restrict__ X,
                    const float* __restrict__ g1, const float* __restrict__ b1,
                    const float* __restrict__ g2, const float* __restrict__ b2,
                    u16* __restrict__ Y1, u16* __restrict__ Y2, int M)
{
    int w0 = blockIdx.x * 4 + (threadIdx.x >> 6);
    int lane = threadIdx.x & 63;
    int stride = gridDim.x * 4;
    for (int row = w0; row < M; row += stride) {
        const float* x = X + (size_t)row * DDIM;
        float v[8], s = 0.0f;
        #pragma unroll
        for (int i = 0; i < 8; i++) { v[i] = x[lane + i * 64]; s += v[i]; }
        #pragma unroll
        for (int off = 32; off; off >>= 1) s += __shfl_xor(s, off, 64);
        float mu = s * (1.0f / 512.0f), q = 0.0f;
        #pragma unroll
        for (int i = 0; i < 8; i++) { float d = v[i] - mu; q += d * d; }
        #pragma unroll
        for (int off = 32; off; off >>= 1) q += __shfl_xor(q, off, 64);
        float inv = 1.0f / sqrtf(q * (1.0f / 512.0f) + 1e-5f);
        u16* y1 = Y1 + (size_t)row * DDIM;
        u16* y2 = Y2 + (size_t)row * DDIM;
        #pragma unroll
        for (int i = 0; i < 8; i++) {
            int c = lane + i * 64;
            float n = (v[i] - mu) * inv;
            y1[c] = f2bf(n * g1[c] + b1[c]);
            y2[c] = f2bf(n * g2[c] + b2[c]);
        }
    }
}

__global__ __launch_bounds__(256)
void patch_kernel(const float* __restrict__ x, u16* __restrict__ xp)
{
    const size_t total = (size_t)MPATCH * PDIM;
    for (size_t idx = (size_t)blockIdx.x * 256 + threadIdx.x; idx < total;
         idx += (size_t)gridDim.x * 256) {
        int pd = (int)(idx % PDIM);
        int bn = (int)(idx / PDIM);
        int n = bn % NPATCH, b = bn / NPATCH;
        int c = pd % 3, pix = pd / 3;
        int px = pix % 16, py = pix / 16;
        int hx = n % 14, hy = n / 14;
        int row = hy * 16 + py, col = hx * 16 + px;
        xp[idx] = f2bf(x[((size_t)(b * 3 + c) * 224 + row) * 224 + col]);
    }
}

__global__ __launch_bounds__(256)
void assemble_kernel(const float* __restrict__ e, const float* __restrict__ clstok,
                     const float* __restrict__ pos, float* __restrict__ U)
{
    const size_t total = (size_t)MTOK * DDIM;
    for (size_t idx = (size_t)blockIdx.x * 256 + threadIdx.x; idx < total;
         idx += (size_t)gridDim.x * 256) {
        int d = (int)(idx % DDIM);
        int bt = (int)(idx / DDIM);
        int t = bt % NTOK, b = bt / NTOK;
        float v = (t == 0) ? clstok[d] : e[((size_t)b * NPATCH + (t - 1)) * DDIM + d];
        U[idx] = v + pos[t * DDIM + d];
    }
}

__global__ __launch_bounds__(256)
void convert7_kernel(const float* s0, const float* s1, const float* s2,
                     const float* s3, const float* s4, const float* s5,
                     const float* s6, u16* __restrict__ dst)
{
    const int total4 = 1409024;  // 5636096/4
    for (int i4 = blockIdx.x * 256 + threadIdx.x; i4 < total4; i4 += gridDim.x * 256) {
        size_t e = (size_t)i4 * 4;
        const float* s; size_t off;
        if      (e < 393216)  { s = s0; off = 0; }
        else if (e < 1179648) { s = s1; off = 393216; }
        else if (e < 1441792) { s = s2; off = 1179648; }
        else if (e < 2490368) { s = s3; off = 1441792; }
        else if (e < 3538944) { s = s4; off = 2490368; }
        else if (e < 4587520) { s = s5; off = 3538944; }
        else                  { s = s6; off = 4587520; }
        float4 v = ((const float4*)s)[(e - off) >> 2];
        dst[e + 0] = f2bf(v.x); dst[e + 1] = f2bf(v.y);
        dst[e + 2] = f2bf(v.z); dst[e + 3] = f2bf(v.w);
    }
}

// ---------------------------------------------------------------------------
// MFMA attention (blocks 0..511) with optional fused halt-mean (blocks 512+).
// ---------------------------------------------------------------------------
template<int HM>
__global__ __launch_bounds__(256)
void attn_hm_kernel(const u16* __restrict__ qkv, u16* __restrict__ O,
                    const float* __restrict__ hsc, const float* __restrict__ bh2,
                    const float* __restrict__ U, float* __restrict__ halts,
                    float* __restrict__ cls, int lidx)
{
    __shared__ u16 Ks[208 * 64];
    __shared__ u16 Vt[64 * 208];
    __shared__ u16 Pl[4 * 16 * 208];

    if (HM && blockIdx.x >= 512) {
        int b = blockIdx.x - 512;
        int ln = threadIdx.x;
        if (ln >= 64) return;
        float bb = bh2[0];
        float s = 0.0f;
        for (int t = ln; t < NTOK; t += 64)
            s += 1.0f / (1.0f + expf(-(hsc[b * NTOK + t] + bb)));
        #pragma unroll
        for (int off = 32; off; off >>= 1) s += __shfl_xor(s, off, 64);
        if (ln == 0) halts[b * NLAYER + lidx] = s * (1.0f / (float)NTOK);
        for (int d = ln; d < DDIM; d += 64)
            cls[((size_t)b * NLAYER + lidx) * DDIM + d] = U[(size_t)b * NTOK * DDIM + d];
        return;
    }

    const int bh = blockIdx.x >> 1;
    const int half = blockIdx.x & 1;
    const int b = bh >> 3, h = bh & 7;
    const int tid = threadIdx.x;
    const int lane = tid & 63, wid = tid >> 6;
    const size_t base = ((size_t)b * NTOK) * 1536 + (size_t)h * 64;

    {
        int j0 = tid >> 3;
        int d0 = (tid & 7) * 8;
        for (int p = 0; p < 7; ++p) {
            int j = p * 32 + j0;
            if (j < 208) {
                bf16x8 v = {};
                if (j < NTOK) v = *(const bf16x8*)&qkv[base + (size_t)j * 1536 + 512 + d0];
                int byt = (j * 128 + d0 * 2) ^ ((j & 7) << 4);
                *(bf16x8*)((char*)Ks + byt) = v;
            }
        }
    }
    {
        int d = tid & 63;
        int jg = tid >> 6;
        for (int j = jg * 52; j < jg * 52 + 52; ++j) {
            u16 v = (j < NTOK) ? qkv[base + (size_t)j * 1536 + 1024 + d] : (u16)0;
            int byt = (d * 416 + j * 2) ^ ((d & 7) << 4);
            *(u16*)((char*)Vt + byt) = v;
        }
    }
    __syncthreads();

    u16* Pw = Pl + wid * 16 * 208;
    const float scale = 0.04419417382415922f;
    const int t0   = half ? 7 : 0;
    const int tcnt = half ? 6 : 7;
    const int g = lane >> 4;
    const int mycol = lane & 15;

    for (int ti = wid; ti < tcnt; ti += 4) {
        const int r0 = (t0 + ti) * 16;
        bf16x8 qf[2];
        #pragma unroll
        for (int ks = 0; ks < 2; ++ks) {
            int row = r0 + mycol;
            int col = ks * 32 + (g << 3);
            qf[ks] = *(const bf16x8*)&qkv[base + (size_t)row * 1536 + col];
        }
        f32x4 s[13];
        #pragma unroll
        for (int ct = 0; ct < 13; ++ct) s[ct] = (f32x4){0.f, 0.f, 0.f, 0.f};
        #pragma unroll
        for (int ks = 0; ks < 2; ++ks) {
            int kbyte = (ks * 32 + (g << 3)) * 2;
            #pragma unroll
            for (int ct = 0; ct < 13; ++ct) {
                int n = ct * 16 + mycol;
                bf16x8 kf = *(const bf16x8*)((char*)Ks + ((n * 128 + kbyte) ^ ((n & 7) << 4)));
                s[ct] = __builtin_amdgcn_mfma_f32_16x16x32_bf16(qf[ks], kf, s[ct], 0, 0, 0);
            }
        }
        float m[4], sum[4];
        #pragma unroll
        for (int j = 0; j < 4; ++j) m[j] = -1e30f;
        #pragma unroll
        for (int ct = 0; ct < 13; ++ct) {
            bool valid = (ct * 16 + mycol) < NTOK;
            #pragma unroll
            for (int j = 0; j < 4; ++j) {
                float v = valid ? s[ct][j] * scale : -1e30f;
                s[ct][j] = v;
                m[j] = fmaxf(m[j], v);
            }
        }
        #pragma unroll
        for (int off = 1; off < 16; off <<= 1)
            #pragma unroll
            for (int j = 0; j < 4; ++j) m[j] = fmaxf(m[j], __shfl_xor(m[j], off, 64));
        #pragma unroll
        for (int j = 0; j < 4; ++j) sum[j] = 0.0f;
        #pragma unroll
        for (int ct = 0; ct < 13; ++ct)
            #pragma unroll
            for (int j = 0; j < 4; ++j) {
                float e = expf(s[ct][j] - m[j]);
                s[ct][j] = e;
                sum[j] += e;
            }
        #pragma unroll
        for (int off = 1; off < 16; off <<= 1)
            #pragma unroll
            for (int j = 0; j < 4; ++j) sum[j] += __shfl_xor(sum[j], off, 64);
        float inv[4];
        #pragma unroll
        for (int j = 0; j < 4; ++j) inv[j] = 1.0f / sum[j];
        #pragma unroll
        for (int ct = 0; ct < 13; ++ct) {
            int col = ct * 16 + mycol;
            #pragma unroll
            for (int j = 0; j < 4; ++j) {
                int row = (g << 2) + j;
                int byt = (row * 416 + col * 2) ^ ((row & 7) << 4);
                *(u16*)((char*)Pw + byt) = f2bf(s[ct][j] * inv[j]);
            }
        }
        #pragma unroll
        for (int nt = 0; nt < 4; ++nt) {
            f32x4 o = (f32x4){0.f, 0.f, 0.f, 0.f};
            #pragma unroll
            for (int ks = 0; ks < 7; ++ks) {
                bf16x8 pf = {}, vf = {};
                bool live = !(ks == 6 && g >= 2);
                if (live) {
                    int kbyte = (ks * 32 + (g << 3)) * 2;
                    pf = *(const bf16x8*)((char*)Pw + ((mycol * 416 + kbyte) ^ ((mycol & 7) << 4)));
                    int vrow = nt * 16 + mycol;
                    vf = *(const bf16x8*)((char*)Vt + ((vrow * 416 + kbyte) ^ ((vrow & 7) << 4)));
                }
                o = __builtin_amdgcn_mfma_f32_16x16x32_bf16(pf, vf, o, 0, 0, 0);
            }
            #pragma unroll
            for (int j = 0; j < 4; ++j) {
                int grow = r0 + (g << 2) + j;
                if (grow < NTOK)
                    O[((size_t)b * NTOK + grow) * DDIM + h * 64 + nt * 16 + mycol] = f2bf(o[j]);
            }
        }
    }
}

__global__ __launch_bounds__(64)
void haltmean_kernel(const float* __restrict__ hsc, const float* __restrict__ bh2,
                     const float* __restrict__ U, float* __restrict__ halts,
                     float* __restrict__ cls, int lidx)
{
    int b = blockIdx.x, lane = threadIdx.x;
    float bb = bh2[0];
    float s = 0.0f;
    for (int t = lane; t < NTOK; t += 64)
        s += 1.0f / (1.0f + expf(-(hsc[b * NTOK + t] + bb)));
    #pragma unroll
    for (int off = 32; off; off >>= 1) s += __shfl_xor(s, off, 64);
    if (lane == 0) halts[b * NLAYER + lidx] = s * (1.0f / (float)NTOK);
    for (int d = lane; d < DDIM; d += 64)
        cls[((size_t)b * NLAYER + lidx) * DDIM + d] = U[(size_t)b * NTOK * DDIM + d];
}

__global__ __launch_bounds__(256)
void head_logits_kernel(const u16* __restrict__ Hh, const float* __restrict__ Wc2,
                        const float* __restrict__ bc2, float* __restrict__ logits)
{
    int wave = (blockIdx.x * 4) + (threadIdx.x >> 6);
    int lane = threadIdx.x & 63;
    if (wave >= BBATCH * NLAYER) return;
    const u16* row = Hh + (size_t)wave * MLPDIM;
    float rv[32];
    #pragma unroll
    for (int i = 0; i < 32; i++) rv[i] = bf2f(row[lane + i * 64]);
    #pragma unroll
    for (int c = 0; c < NCLASS; c++) {
        float s = 0.0f;
        #pragma unroll
        for (int i = 0; i < 32; i++) s = fmaf(rv[i], Wc2[c * MLPDIM + lane + i * 64], s);
        #pragma unroll
        for (int off = 32; off; off >>= 1) s += __shfl_xor(s, off, 64);
        if (lane == 0) logits[wave * NCLASS + c] = s + bc2[c];
    }
}

__global__ __launch_bounds__(256)
void celoss_kernel(const float* __restrict__ logits, const int* __restrict__ y,
                   const float* __restrict__ halts, float* __restrict__ out)
{
    __shared__ float ceS[BBATCH * NLAYER];
    __shared__ float bl[BBATCH];
    int tid = threadIdx.x;
    for (int r = tid; r < BBATCH * NLAYER; r += 256) {
        const float* lg = logits + (size_t)r * NCLASS;
        float mx = lg[0];
        #pragma unroll
        for (int i = 1; i < NCLASS; i++) mx = fmaxf(mx, lg[i]);
        float s = 0.0f;
        #pragma unroll
        for (int i = 0; i < NCLASS; i++) s += expf(lg[i] - mx);
        int lab = y[r / NLAYER];
        ceS[r] = -(lg[lab] - mx - logf(s));
    }
    __syncthreads();
    if (tid < BBATCH) {
        const float* c = ceS + tid * NLAYER;
        int idx = 0; float mn = c[0];
        for (int l = 1; l < NLAYER; l++) if (c[l] < mn) { mn = c[l]; idx = l; }
        idx += 1;
        float acc = 0.0f;
        for (int l = 0; l < idx; l++) {
            acc += c[l];
            float p = halts[tid * NLAYER + l];
            p = fminf(fmaxf(p, 1e-7f), 1.0f - 1e-7f);
            float hl = (l == idx - 1) ? 0.0f : 1.0f;
            acc += -(hl * logf(p) + (1.0f - hl) * log1pf(-p));
        }
        bl[tid] = acc / (float)idx;
    }
    __syncthreads();
    if (tid == 0) {
        float t = 0.0f;
        for (int b = 0; b < BBATCH; b++) t += bl[b];
        out[0] = t * (1.0f / (float)BBATCH);
    }
}

extern "C" void kernel_launch(void* const* d_in, const int* in_sizes, int n_in,
                              void* d_out, int out_size, void* d_ws, size_t ws_size,
                              hipStream_t stream)
{
    const float* x      = (const float*)d_in[0];
    const int*   y      = (const int*)d_in[1];
    const float* pos    = (const float*)d_in[2];
    const float* clstok = (const float*)d_in[3];
    const float* Wp     = (const float*)d_in[4];
    const float* bp     = (const float*)d_in[5];
    const float* Wqkv   = (const float*)d_in[6];
    const float* Wo     = (const float*)d_in[7];
    const float* bo     = (const float*)d_in[8];
    const float* ln1g   = (const float*)d_in[9];
    const float* ln1b   = (const float*)d_in[10];
    const float* ln2g   = (const float*)d_in[11];
    const float* ln2b   = (const float*)d_in[12];
    const float* W1     = (const float*)d_in[13];
    const float* b1     = (const float*)d_in[14];
    const float* W2     = (const float*)d_in[15];
    const float* b2     = (const float*)d_in[16];
    const float* lnhg   = (const float*)d_in[17];
    const float* lnhb   = (const float*)d_in[18];
    const float* Wh1    = (const float*)d_in[19];
    const float* bh1    = (const float*)d_in[20];
    const float* Wh2    = (const float*)d_in[21];
    const float* bh2    = (const float*)d_in[22];
    const float* lncg   = (const float*)d_in[23];
    const float* lncb   = (const float*)d_in[24];
    const float* Wc1    = (const float*)d_in[25];
    const float* bc1    = (const float*)d_in[26];
    const float* Wc2    = (const float*)d_in[27];
    const float* bc2    = (const float*)d_in[28];

    // ---- workspace layout ----
    float* U      = (float*)d_ws;                         // MTOK*512 f32
    float* CLS    = U + (size_t)MTOK * DDIM;              // 320*512
    float* LOGITS = CLS + (size_t)BBATCH * NLAYER * DDIM; // 3200
    float* HSC    = LOGITS + BBATCH * NLAYER * NCLASS;    // 10*MTOK
    float* HALTS  = HSC + (size_t)NLAYER * MTOK;          // 320
    u16* QKVb = (u16*)(HALTS + BBATCH * NLAYER + 32);     // QKVROWS*1536 (aliases EMB)
    float* EMB = (float*)QKVb;                            // MPATCH*512 f32 (pre-loop only)
    u16* LNB1 = QKVb + (size_t)QKVROWS * 1536;            // MPAD*512
    u16* LNB2 = LNB1 + (size_t)MPAD * DDIM;               // MPAD*512
    u16* LNBh = LNB2 + (size_t)MPAD * DDIM;               // MPAD*512
    u16* HB   = LNBh + (size_t)MPAD * DDIM;               // MPAD*2048 (aliases XP)
    u16* XP   = HB;                                       // MPATCH*768 (pre-loop only)
    u16* CLNB = HB + (size_t)MPAD * MLPDIM;               // 384*512
    u16* wWp  = CLNB + 384 * DDIM;
    u16* wWqkv= wWp   + 512 * 768;
    u16* wWo  = wWqkv + 1536 * 512;
    u16* wW1  = wWo   + 512 * 512;
    u16* wW2  = wW1   + 2048 * 512;
    u16* wWh1 = wW2   + 512 * 2048;
    u16* wWc1 = wWh1  + 2048 * 512;

    dim3 blk(256);
    const float* dummyF = bh2;

    // ---- setup ----
    convert7_kernel<<<dim3(1024), blk, 0, stream>>>(Wp, Wqkv, Wo, W1, W2, Wh1, Wc1, wWp);
    hipMemsetAsync(HSC, 0, (size_t)NLAYER * MTOK * sizeof(float), stream);
    patch_kernel<<<dim3(2048), blk, 0, stream>>>(x, XP);
    // patch embed: 49 m-tiles x 4 n-tiles, K=768 (12 phases), mode 3 (f32+bias)
    mg_kernel<<<dim3(196), blk, 0, stream>>>(
        196, PDIM, MPATCH,
        XP, wWp, bp, nullptr, (void*)EMB, DDIM, 3, 4, 0, 12,
        XP, wWp, bp, nullptr, (void*)EMB, DDIM, 3, 4, 0, 12);
    assemble_kernel<<<dim3(2048), blk, 0, stream>>>(EMB, clstok, pos, U);
    ln_dual_kernel<<<dim3(512), blk, 0, stream>>>(U, ln1g, ln1b, lnhg, lnhb, LNB1, LNBh, MTOK);

    for (int l = 0; l < NLAYER; l++) {
        // 1: QKV GEMM (+ halt GEMM of layer l-1)
        if (l == 0) {
            mg_kernel<<<dim3(600), blk, 0, stream>>>(
                600, DDIM, MTOK,
                LNB1, wWqkv, nullptr, nullptr, (void*)QKVb, 1536, 0, 12, 0, 8,
                LNB1, wWqkv, nullptr, nullptr, (void*)QKVb, 1536, 0, 12, 0, 8);
        } else {
            mg_kernel<<<dim3(1400), blk, 0, stream>>>(
                600, DDIM, MTOK,
                LNB1, wWqkv, nullptr, nullptr, (void*)QKVb, 1536, 0, 12, 0, 8,
                LNBh, wWh1, bh1, Wh2, (void*)(HSC + (size_t)(l - 1) * MTOK), 2048, 1, 16, 0, 8);
        }
        // 2: attn (+ halt-mean of layer l-1)
        if (l == 0) {
            attn_hm_kernel<0><<<dim3(512), blk, 0, stream>>>(
                QKVb, LNB1, nullptr, dummyF, U, HALTS, CLS, 0);
        } else {
            attn_hm_kernel<1><<<dim3(544), blk, 0, stream>>>(
                QKVb, LNB1, HSC + (size_t)(l - 1) * MTOK, bh2, U, HALTS, CLS, l - 1);
        }
        // 3: Wo + bias + residual -> U (f32)
        mg_kernel<<<dim3(200), blk, 0, stream>>>(
            200, DDIM, MTOK,
            LNB1, wWo, bo, U, (void*)U, DDIM, 3, 4, 0, 8,
            LNB1, wWo, bo, U, (void*)U, DDIM, 3, 4, 0, 8);
        // 4: ln2
        ln_one_kernel<<<dim3(512), blk, 0, stream>>>(U, ln2g, ln2b, LNB2, MTOK);
        // 5: W1 + bias + gelu -> HB (bf16)
        mg_kernel<<<dim3(800), blk, 0, stream>>>(
            800, DDIM, MTOK,
            LNB2, wW1, b1, nullptr, (void*)HB, MLPDIM, 2, 16, 0, 8,
            LNB2, wW1, b1, nullptr, (void*)HB, MLPDIM, 2, 16, 0, 8);
        // 6: W2 split-K2, atomic += into U (bias on region A only)
        mg_kernel<<<dim3(400), blk, 0, stream>>>(
            200, MLPDIM, MTOK,
            HB, wW2, b2, nullptr, (void*)U, DDIM, 4, 4, 0, 16,
            HB, wW2, nullptr, nullptr, (void*)U, DDIM, 4, 4, 1024, 16);
        // 7: fused ln1 + lnh of new U
        ln_dual_kernel<<<dim3(512), blk, 0, stream>>>(
            U, ln1g, ln1b, lnhg, lnhb, LNB1, LNBh, MTOK);
    }

    // final halt GEMM (layer 9) + halt-mean
    mg_kernel<<<dim3(800), blk, 0, stream>>>(
        800, DDIM, MTOK,
        LNBh, wWh1, bh1, Wh2, (void*)(HSC + (size_t)9 * MTOK), 2048, 1, 16, 0, 8,
        LNBh, wWh1, bh1, Wh2, (void*)(HSC + (size_t)9 * MTOK), 2048, 1, 16, 0, 8);
    haltmean_kernel<<<dim3(BBATCH), dim3(64), 0, stream>>>(
        HSC + (size_t)9 * MTOK, bh2, U, HALTS, CLS, 9);

    // head
    ln_one_kernel<<<dim3(80), blk, 0, stream>>>(CLS, lncg, lncb, CLNB, BBATCH * NLAYER);
    mg_kernel<<<dim3(48), blk, 0, stream>>>(
        48, DDIM, BBATCH * NLAYER,
        CLNB, wWc1, bc1, nullptr, (void*)HB, MLPDIM, 2, 16, 0, 8,
        CLNB, wWc1, bc1, nullptr, (void*)HB, MLPDIM, 2, 16, 0, 8);
    head_logits_kernel<<<dim3(80), blk, 0, stream>>>(HB, Wc2, bc2, LOGITS);
    celoss_kernel<<<dim3(1), blk, 0, stream>>>(LOGITS, y, HALTS, (float*)d_out);
}